// Round 5
// baseline (5126.180 us; speedup 1.0000x reference)
//
#include <hip/hip_runtime.h>
#include <hip/hip_bf16.h>

typedef __hip_bfloat16 bf16;
typedef __attribute__((ext_vector_type(8))) short short8;
typedef __attribute__((ext_vector_type(4))) short short4v;
typedef __attribute__((ext_vector_type(4))) float f32x4;

#define AGT __HIP_MEMORY_SCOPE_AGENT
#define RLX __ATOMIC_RELAXED
#define NBLK 192
#define SMEM_BYTES 147456
#define W0_STRIDE 1152   // bytes per L0 LDS weight row; 1152 = 9*128 -> XOR swizzle row-closed

__device__ __forceinline__ float sigm(float x) { return 1.0f / (1.0f + __expf(-x)); }

__device__ __forceinline__ short f2bf(float f) {
    union { float f; unsigned int u; } v; v.f = f;
    unsigned int r = v.u + 0x7fffu + ((v.u >> 16) & 1u);
    return (short)(r >> 16);
}

// ---------------- workspace layout ----------------
#define WS_H0      0x000000   // 2 x 256x512 bf16 = 512KB
#define WS_H1      0x080000   // 512KB
#define WS_PART    0x100000   // [32][256][8] f32 = 256KB
#define WS_ARRIVE  0x140000   // 192 x 128B flags
#define WS_RELEASE 0x148000   // 4B
#define WS_XBF     0x150000   // src bf16 [256][168][8] = 672KB
#define WS_W       0x200000   // 6 x 2MB bf16 big weights
#define WS_EWIH0   0xE00000   // 2048x8 bf16 = 32KB
#define WS_DWIH0   0xE08000
#define WS_ZERO_BYTES 0x150000

// ---------------- fp32 -> bf16 conversion ----------------
struct CvtEntry { const float* s; bf16* d; int n; };
struct CvtArgs  { CvtEntry e[9]; };

__global__ __launch_bounds__(256) void convert_kernel(CvtArgs a)
{
    CvtEntry en = a.e[blockIdx.y];
    int n4 = en.n >> 2;
    const float4* s4 = (const float4*)en.s;
    short4v* d4 = (short4v*)en.d;
    for (int i = blockIdx.x * blockDim.x + threadIdx.x; i < n4;
         i += gridDim.x * blockDim.x) {
        float4 f = s4[i];
        short4v o;
        o[0] = f2bf(f.x); o[1] = f2bf(f.y); o[2] = f2bf(f.z); o[3] = f2bf(f.w);
        d4[i] = o;
    }
}

__global__ void init_kernel(unsigned int* ws)
{
    const int total = WS_ZERO_BYTES / 4;
    for (int i = blockIdx.x * blockDim.x + threadIdx.x; i < total;
         i += gridDim.x * blockDim.x)
        ws[i] = 0u;
}

// ---------------- kernel args ----------------
struct KArgs {
    const bf16 *xbf;
    const bf16 *eWhh0, *eWih1, *eWhh1, *dWhh0, *dWih1, *dWhh1, *eWih0, *dWih0;
    const float *ebih0, *ebhh0, *ebih1, *ebhh1, *dbih0, *dbhh0, *dbih1, *dbhh1;
    const float *fcW, *fcb;
    bf16 *h0a, *h0b, *h1a, *h1b;
    float *partials;
    unsigned *arrive, *release;
    float *outp;
};

// ---------------- grid barrier ----------------
__device__ __forceinline__ void gbar(unsigned* arrive, unsigned* release_f, unsigned gen)
{
    __syncthreads();   // waves drain vmcnt -> stores at L2 before publish
    if (blockIdx.x == 0) {
        if (threadIdx.x == 0)
            __hip_atomic_store(arrive, gen, __ATOMIC_RELEASE, AGT);
        if (threadIdx.x < NBLK) {
            while (__hip_atomic_load(arrive + threadIdx.x * 32, RLX, AGT) < gen)
                __builtin_amdgcn_s_sleep(1);
        }
        __syncthreads();
        if (threadIdx.x == 0)
            __hip_atomic_store(release_f, gen, __ATOMIC_RELEASE, AGT);
    } else {
        if (threadIdx.x == 0) {
            __hip_atomic_store(arrive + blockIdx.x * 32, gen, __ATOMIC_RELEASE, AGT);
            while (__hip_atomic_load(release_f, RLX, AGT) < gen)
                __builtin_amdgcn_s_sleep(1);
        }
    }
    if (threadIdx.x == 0)
        (void)__hip_atomic_load(release_f, __ATOMIC_ACQUIRE, AGT);  // L1/L2 inv
    __syncthreads();
}

// ---------------- LDS weight loaders ----------------
// L0: 64 rows (g*16+jl), stride 1152B: bytes [0,1024) Whh XOR-swizzled (8 full
// 128B blocks -> closed), [1024,1088) Wih0 x-slot unswizzled, [1088,1152) pad.
__device__ __forceinline__ void load_w0(char* lw, const bf16* Whh, const bf16* Wih, int j0, int tid)
{
    for (int u = tid; u < 64 * 68; u += 512) {
        int row = u / 68, uc = u - row * 68;
        int n = ((row >> 4) << 9) + j0 + (row & 15);
        int colel = uc << 3;
        short8 v = {0, 0, 0, 0, 0, 0, 0, 0};
        if (colel < 512)       v = *(const short8*)(Whh + (size_t)n * 512 + colel);
        else if (colel == 512) v = *(const short8*)(Wih + (size_t)n * 8);
        int off = row * W0_STRIDE + uc * 16;
        if (uc < 64) off ^= (row & 7) << 4;
        *(short8*)(lw + off) = v;
    }
}
// L1: 64 rows x 1024 el (cols 0..511 Wih1, 512..1023 Whh1), swizzled (2048B stride, closed)
__device__ __forceinline__ void load_w1(char* lw, const bf16* Wih, const bf16* Whh, int j0, int tid)
{
    for (int u = tid; u < 64 * 128; u += 512) {
        int row = u >> 7, uc = u & 127;
        int n = ((row >> 4) << 9) + j0 + (row & 15);
        int colel = uc << 3;
        short8 v;
        if (colel < 512) v = *(const short8*)(Wih + (size_t)n * 512 + colel);
        else             v = *(const short8*)(Whh + (size_t)n * 512 + (colel - 512));
        *(short8*)(lw + ((row * 2048 + uc * 16) ^ ((row & 7) << 4))) = v;
    }
}

// ---------------- layer-0 step (64 blocks: 2 m-halves x 32 j-blocks) ----------------
template<bool DEC>
__device__ __forceinline__ void l0_step(
    const bf16* __restrict__ h0cur, bf16* __restrict__ h0nxt,
    const bf16* __restrict__ xbf, int s,
    const float* __restrict__ partials, const float* __restrict__ fcb,
    float* __restrict__ outp, int t,
    char* lw, float* lgl, bf16* lxs,
    float* cst, const float* bsum,
    int m0, int j0, int jb, int tid)
{
    const int w = tid >> 6, g = w & 3, kh = w >> 2;
    const int l = tid & 63, lr = l & 15, lg = l >> 4;

    if (DEC) {
        // build x_stage (t==0: last src step; t>0: reduce fc partials = pred[t-1])
        #pragma unroll
        for (int p = 0; p < 2; ++p) {
            int e = p * 512 + tid, mlo = e >> 3, f = e & 7;
            if (t == 0) {
                lxs[mlo * 8 + f] = xbf[((size_t)(m0 + mlo) * 168 + 167) * 8 + f];
            } else {
                float sacc = fcb[f];
                #pragma unroll 8
                for (int q = 0; q < 32; ++q)
                    sacc += partials[q * 2048 + (m0 + mlo) * 8 + f];
                if (jb == 0) outp[(size_t)(m0 + mlo) * 192 + (t - 1) * 8 + f] = sacc;
                ((short*)lxs)[mlo * 8 + f] = f2bf(sacc);
            }
        }
        __syncthreads();
    }

    f32x4 acc[8];
    #pragma unroll
    for (int i = 0; i < 8; ++i) acc[i] = (f32x4){0.f, 0.f, 0.f, 0.f};
    const int wrow = g * 16 + lr;

    if (kh == 0) {
        #pragma unroll
        for (int kcg = 0; kcg < 9; ++kcg) {
            short8 bfr = *(const short8*)(lw + ((wrow * W0_STRIDE + kcg * 64 + lg * 16) ^ ((wrow & 7) << 4)));
            #pragma unroll
            for (int mt = 0; mt < 8; ++mt) {
                short8 av = *(const short8*)(h0cur + ((size_t)(m0 + mt * 16 + lr) << 9) + kcg * 32 + lg * 8);
                acc[mt] = __builtin_amdgcn_mfma_f32_16x16x32_bf16(av, bfr, acc[mt], 0, 0, 0);
            }
        }
    } else {
        #pragma unroll
        for (int kcg = 9; kcg < 17; ++kcg) {
            int off = wrow * W0_STRIDE + kcg * 64 + lg * 16;
            if (kcg < 16) off ^= (wrow & 7) << 4;   // x-slot region is unswizzled
            short8 bfr = *(const short8*)(lw + off);
            #pragma unroll
            for (int mt = 0; mt < 8; ++mt) {
                short8 av;
                if (kcg < 16) {
                    av = *(const short8*)(h0cur + ((size_t)(m0 + mt * 16 + lr) << 9) + kcg * 32 + lg * 8);
                } else {
                    short8 z = {0, 0, 0, 0, 0, 0, 0, 0};
                    av = z;
                    if (lg == 0) {
                        if (DEC) av = *(const short8*)(lxs + (mt * 16 + lr) * 8);
                        else     av = *(const short8*)(xbf + ((size_t)(m0 + mt * 16 + lr) * 168 + s) * 8);
                    }
                }
                acc[mt] = __builtin_amdgcn_mfma_f32_16x16x32_bf16(av, bfr, acc[mt], 0, 0, 0);
            }
        }
    }

    __syncthreads();
    if (kh == 0) {
        #pragma unroll
        for (int mt = 0; mt < 8; ++mt)
            #pragma unroll
            for (int r = 0; r < 4; ++r)
                lgl[(g * 128 + mt * 16 + lg * 4 + r) * 16 + lr] = acc[mt][r];
    }
    __syncthreads();
    if (kh == 1) {
        #pragma unroll
        for (int mt = 0; mt < 8; ++mt)
            #pragma unroll
            for (int r = 0; r < 4; ++r)
                lgl[(g * 128 + mt * 16 + lg * 4 + r) * 16 + lr] += acc[mt][r];
    }
    __syncthreads();

    const int jl = tid & 15, mb = tid >> 4;
    #pragma unroll
    for (int p = 0; p < 4; ++p) {
        int ml = p * 32 + mb;
        float gi = lgl[(0 * 128 + ml) * 16 + jl] + bsum[0];
        float gf = lgl[(1 * 128 + ml) * 16 + jl] + bsum[1];
        float gg = lgl[(2 * 128 + ml) * 16 + jl] + bsum[2];
        float go = lgl[(3 * 128 + ml) * 16 + jl] + bsum[3];
        float cv = sigm(gf) * cst[p] + sigm(gi) * tanhf(gg);
        float hv = sigm(go) * tanhf(cv);
        cst[p] = cv;
        ((short*)h0nxt)[((size_t)(m0 + ml) << 9) + j0 + jl] = f2bf(hv);
    }
}

// ---------------- layer-1 step (128 blocks: 4 m-quarters x 32 j-blocks) ----------------
template<bool DEC>
__device__ __forceinline__ void l1_step(
    const bf16* __restrict__ h0src, const bf16* __restrict__ h1prev, bf16* __restrict__ h1nxt,
    float* __restrict__ partials, const float* __restrict__ wf,
    char* lw, float* lgl,
    float* cst, const float* bsum,
    int m0, int j0, int jb, int tid)
{
    const int w = tid >> 6, g = w & 3;
    const int l = tid & 63, lr = l & 15, lg = l >> 4;
    const bf16* A = (w < 4) ? h0src : h1prev;
    const int colbase = (w < 4) ? 0 : 1024;   // BYTES: Whh1 half starts at 512 el = 1024 B
    const int wrow = g * 16 + lr;

    f32x4 acc[4];
    #pragma unroll
    for (int i = 0; i < 4; ++i) acc[i] = (f32x4){0.f, 0.f, 0.f, 0.f};

    #pragma unroll
    for (int kc = 0; kc < 16; ++kc) {
        short8 bfr = *(const short8*)(lw + ((wrow * 2048 + colbase + kc * 64 + lg * 16) ^ ((wrow & 7) << 4)));
        #pragma unroll
        for (int mt = 0; mt < 4; ++mt) {
            short8 av = *(const short8*)(A + ((size_t)(m0 + mt * 16 + lr) << 9) + kc * 32 + lg * 8);
            acc[mt] = __builtin_amdgcn_mfma_f32_16x16x32_bf16(av, bfr, acc[mt], 0, 0, 0);
        }
    }

    __syncthreads();
    if (w < 4) {
        #pragma unroll
        for (int mt = 0; mt < 4; ++mt)
            #pragma unroll
            for (int r = 0; r < 4; ++r)
                lgl[(g * 64 + mt * 16 + lg * 4 + r) * 16 + lr] = acc[mt][r];
    }
    __syncthreads();
    if (w >= 4) {
        #pragma unroll
        for (int mt = 0; mt < 4; ++mt)
            #pragma unroll
            for (int r = 0; r < 4; ++r)
                lgl[(g * 64 + mt * 16 + lg * 4 + r) * 16 + lr] += acc[mt][r];
    }
    __syncthreads();

    const int jl = tid & 15, mb = tid >> 4;
    #pragma unroll
    for (int p = 0; p < 2; ++p) {
        int ml = p * 32 + mb;
        float gi = lgl[(0 * 64 + ml) * 16 + jl] + bsum[0];
        float gf = lgl[(1 * 64 + ml) * 16 + jl] + bsum[1];
        float gg = lgl[(2 * 64 + ml) * 16 + jl] + bsum[2];
        float go = lgl[(3 * 64 + ml) * 16 + jl] + bsum[3];
        float cv = sigm(gf) * cst[p] + sigm(gi) * tanhf(gg);
        float hv = sigm(go) * tanhf(cv);
        cst[p] = cv;
        ((short*)h1nxt)[((size_t)(m0 + ml) << 9) + j0 + jl] = f2bf(hv);
        if (DEC) {
            #pragma unroll
            for (int f = 0; f < 8; ++f) {
                float v = hv * wf[f];
                v += __shfl_xor(v, 1); v += __shfl_xor(v, 2);
                v += __shfl_xor(v, 4); v += __shfl_xor(v, 8);
                if (jl == f)
                    partials[jb * 2048 + (m0 + ml) * 8 + f] = v;
            }
        }
    }
}

// ---------------- persistent kernel ----------------
__global__ __launch_bounds__(512, 2) void net_kernel(KArgs a)
{
    extern __shared__ char smem[];
    const int tid = threadIdx.x;
    const int bid = blockIdx.x;
    const int role = (bid < 64) ? 0 : 1;
    const int sub = role == 0 ? bid : bid - 64;
    const int jb = sub & 31;
    const int mh = sub >> 5;
    const int m0 = (role == 0) ? mh * 128 : mh * 64;
    const int j0 = jb * 16;

    char* lw  = smem;
    float* lgl = (float*)(smem + (role == 0 ? 64 * W0_STRIDE : 131072));
    bf16* lxs  = (bf16*)(smem + 64 * W0_STRIDE + 32768);

    if (role == 0) load_w0(lw, a.eWhh0, a.eWih0, j0, tid);
    else           load_w1(lw, a.eWih1, a.eWhh1, j0, tid);

    float bsum[4];
    {
        const float* bi = role == 0 ? a.ebih0 : a.ebih1;
        const float* bh = role == 0 ? a.ebhh0 : a.ebhh1;
        #pragma unroll
        for (int g2 = 0; g2 < 4; ++g2) {
            int n = (g2 << 9) + j0 + (tid & 15);
            bsum[g2] = bi[n] + bh[n];
        }
    }
    float cst[4] = {0.f, 0.f, 0.f, 0.f};
    __syncthreads();

    bf16* H0[2] = { a.h0a, a.h0b };
    bf16* H1[2] = { a.h1a, a.h1b };
    unsigned gen = 1;

    // -------- encoder: superstep s: L0 computes h0^(s+1), L1 computes h1^(s) --------
    for (int s = 0; s <= 168; ++s) {
        if (role == 0) {
            if (s < 168)
                l0_step<false>(H0[s & 1], H0[(s + 1) & 1], a.xbf, s,
                               nullptr, nullptr, nullptr, 0,
                               lw, lgl, lxs, cst, bsum, m0, j0, jb, tid);
        } else {
            if (s >= 1)
                l1_step<false>(H0[s & 1], H1[(s + 1) & 1], H1[s & 1],
                               nullptr, nullptr, lw, lgl, cst, bsum, m0, j0, jb, tid);
        }
        gbar(a.arrive, a.release, gen++);
    }

    // -------- switch to decoder weights --------
    if (role == 0) load_w0(lw, a.dWhh0, a.dWih0, j0, tid);
    else           load_w1(lw, a.dWih1, a.dWhh1, j0, tid);
    {
        const float* bi = role == 0 ? a.dbih0 : a.dbih1;
        const float* bh = role == 0 ? a.dbhh0 : a.dbhh1;
        #pragma unroll
        for (int g2 = 0; g2 < 4; ++g2) {
            int n = (g2 << 9) + j0 + (tid & 15);
            bsum[g2] = bi[n] + bh[n];
        }
    }
    float wf[8] = {0.f, 0.f, 0.f, 0.f, 0.f, 0.f, 0.f, 0.f};
    if (role == 1) {
        #pragma unroll
        for (int f = 0; f < 8; ++f) wf[f] = a.fcW[f * 512 + j0 + (tid & 15)];
    }
    __syncthreads();

    // -------- decoder: per step: phase A (L0 + pred reduce) | phase B (L1 + fc partials) --------
    for (int t = 0; t < 24; ++t) {
        if (role == 0)
            l0_step<true>(H0[t & 1], H0[(t + 1) & 1], a.xbf, 0,
                          a.partials, a.fcb, a.outp, t,
                          lw, lgl, lxs, cst, bsum, m0, j0, jb, tid);
        gbar(a.arrive, a.release, gen++);
        if (role == 1)
            l1_step<true>(H0[(t + 1) & 1], H1[t & 1], H1[(t + 1) & 1],
                          a.partials, wf, lw, lgl, cst, bsum, m0, j0, jb, tid);
        gbar(a.arrive, a.release, gen++);
    }

    // -------- final pred[23] --------
    if (role == 0 && jb == 0) {
        #pragma unroll
        for (int p = 0; p < 2; ++p) {
            int e = p * 512 + tid, mlo = e >> 3, f = e & 7;
            float sacc = a.fcb[f];
            #pragma unroll 8
            for (int q = 0; q < 32; ++q)
                sacc += a.partials[q * 2048 + (m0 + mlo) * 8 + f];
            a.outp[(size_t)(m0 + mlo) * 192 + 23 * 8 + f] = sacc;
        }
    }
}

extern "C" void kernel_launch(void* const* d_in, const int* in_sizes, int n_in,
                              void* d_out, int out_size, void* d_ws, size_t ws_size,
                              hipStream_t stream)
{
    (void)in_sizes; (void)n_in; (void)out_size; (void)ws_size;
    const float* src   = (const float*)d_in[0];
    const float* eWih0 = (const float*)d_in[1];
    const float* eWhh0 = (const float*)d_in[2];
    const float* ebih0 = (const float*)d_in[3];
    const float* ebhh0 = (const float*)d_in[4];
    const float* eWih1 = (const float*)d_in[5];
    const float* eWhh1 = (const float*)d_in[6];
    const float* ebih1 = (const float*)d_in[7];
    const float* ebhh1 = (const float*)d_in[8];
    const float* dWih0 = (const float*)d_in[9];
    const float* dWhh0 = (const float*)d_in[10];
    const float* dbih0 = (const float*)d_in[11];
    const float* dbhh0 = (const float*)d_in[12];
    const float* dWih1 = (const float*)d_in[13];
    const float* dWhh1 = (const float*)d_in[14];
    const float* dbih1 = (const float*)d_in[15];
    const float* dbhh1 = (const float*)d_in[16];
    const float* fcW   = (const float*)d_in[17];
    const float* fcb   = (const float*)d_in[18];

    char* ws = (char*)d_ws;
    const int NH = 2048 * 512;

    CvtArgs ca;
    ca.e[0] = { eWhh0, (bf16*)(ws + WS_W + 0x000000), NH };
    ca.e[1] = { eWih1, (bf16*)(ws + WS_W + 0x200000), NH };
    ca.e[2] = { eWhh1, (bf16*)(ws + WS_W + 0x400000), NH };
    ca.e[3] = { dWhh0, (bf16*)(ws + WS_W + 0x600000), NH };
    ca.e[4] = { dWih1, (bf16*)(ws + WS_W + 0x800000), NH };
    ca.e[5] = { dWhh1, (bf16*)(ws + WS_W + 0xA00000), NH };
    ca.e[6] = { eWih0, (bf16*)(ws + WS_EWIH0), 2048 * 8 };
    ca.e[7] = { dWih0, (bf16*)(ws + WS_DWIH0), 2048 * 8 };
    ca.e[8] = { src,   (bf16*)(ws + WS_XBF),   256 * 168 * 8 };

    KArgs ka;
    ka.xbf   = (const bf16*)(ws + WS_XBF);
    ka.eWhh0 = (const bf16*)(ws + WS_W + 0x000000);
    ka.eWih1 = (const bf16*)(ws + WS_W + 0x200000);
    ka.eWhh1 = (const bf16*)(ws + WS_W + 0x400000);
    ka.dWhh0 = (const bf16*)(ws + WS_W + 0x600000);
    ka.dWih1 = (const bf16*)(ws + WS_W + 0x800000);
    ka.dWhh1 = (const bf16*)(ws + WS_W + 0xA00000);
    ka.eWih0 = (const bf16*)(ws + WS_EWIH0);
    ka.dWih0 = (const bf16*)(ws + WS_DWIH0);
    ka.ebih0 = ebih0; ka.ebhh0 = ebhh0; ka.ebih1 = ebih1; ka.ebhh1 = ebhh1;
    ka.dbih0 = dbih0; ka.dbhh0 = dbhh0; ka.dbih1 = dbih1; ka.dbhh1 = dbhh1;
    ka.fcW = fcW; ka.fcb = fcb;
    ka.h0a = (bf16*)(ws + WS_H0);
    ka.h0b = (bf16*)(ws + WS_H0 + 0x40000);
    ka.h1a = (bf16*)(ws + WS_H1);
    ka.h1b = (bf16*)(ws + WS_H1 + 0x40000);
    ka.partials = (float*)(ws + WS_PART);
    ka.arrive   = (unsigned*)(ws + WS_ARRIVE);
    ka.release  = (unsigned*)(ws + WS_RELEASE);
    ka.outp     = (float*)d_out;

    hipFuncSetAttribute((const void*)net_kernel,
                        hipFuncAttributeMaxDynamicSharedMemorySize, SMEM_BYTES);

    convert_kernel<<<dim3(128, 9), dim3(256), 0, stream>>>(ca);
    init_kernel<<<dim3(512), dim3(256), 0, stream>>>((unsigned int*)ws);
    net_kernel<<<dim3(NBLK), dim3(512), SMEM_BYTES, stream>>>(ka);
}

// Round 6
// 4353.773 us; speedup vs baseline: 1.1774x; 1.1774x over previous
//
#include <hip/hip_runtime.h>
#include <hip/hip_bf16.h>

typedef __hip_bfloat16 bf16;
typedef __attribute__((ext_vector_type(8))) short short8;
typedef __attribute__((ext_vector_type(4))) short short4v;
typedef __attribute__((ext_vector_type(4))) float f32x4;

#define AGT __HIP_MEMORY_SCOPE_AGENT
#define NBLK 192
#define SMEM_BYTES 147456
#define W0_STRIDE 1152   // bytes per L0 LDS weight row; 9*128 -> XOR swizzle row-closed

__device__ __forceinline__ float sigm(float x) { return 1.0f / (1.0f + __expf(-x)); }

__device__ __forceinline__ short f2bf(float f) {
    union { float f; unsigned int u; } v; v.f = f;
    unsigned int r = v.u + 0x7fffu + ((v.u >> 16) & 1u);
    return (short)(r >> 16);
}

// ---- write-through (coherence-point) memory ops: bypass L1/L2 so no
// ---- release-side buffer_wbl2 is ever needed for cross-block data.
__device__ __forceinline__ void store_short_wt(bf16* p, short v) {
    asm volatile("global_store_short %0, %1, off sc0 sc1"
                 :: "v"(p), "v"((int)(unsigned short)v) : "memory");
}
__device__ __forceinline__ void store_dword_wt(float* p, float v) {
    asm volatile("global_store_dword %0, %1, off sc0 sc1"
                 :: "v"(p), "v"(v) : "memory");
}
__device__ __forceinline__ void store_dword_wt_u(unsigned* p, unsigned v) {
    asm volatile("global_store_dword %0, %1, off sc0 sc1"
                 :: "v"(p), "v"(v) : "memory");
}
__device__ __forceinline__ unsigned load_dword_wt(const unsigned* p) {
    unsigned v;
    asm volatile("global_load_dword %0, %1, off sc0 sc1\n\ts_waitcnt vmcnt(0)"
                 : "=v"(v) : "v"(p) : "memory");
    return v;
}
__device__ __forceinline__ void vmcnt0() {
    asm volatile("s_waitcnt vmcnt(0)" ::: "memory");
}

// ---------------- workspace layout ----------------
#define WS_H0      0x000000   // 2 x 256x512 bf16 = 512KB
#define WS_H1      0x080000   // 512KB
#define WS_PART    0x100000   // [32][256][8] f32 = 256KB
#define WS_ARRIVE  0x140000   // 192 x 128B flags
#define WS_RELEASE 0x148000   // 4B
#define WS_XBF     0x150000   // src bf16 [256][168][8] = 672KB
#define WS_W       0x200000   // 6 x 2MB bf16 big weights
#define WS_EWIH0   0xE00000   // 2048x8 bf16 = 32KB
#define WS_DWIH0   0xE08000
#define WS_ZERO_BYTES 0x150000

// ---------------- fp32 -> bf16 conversion ----------------
struct CvtEntry { const float* s; bf16* d; int n; };
struct CvtArgs  { CvtEntry e[9]; };

__global__ __launch_bounds__(256) void convert_kernel(CvtArgs a)
{
    CvtEntry en = a.e[blockIdx.y];
    int n4 = en.n >> 2;
    const float4* s4 = (const float4*)en.s;
    short4v* d4 = (short4v*)en.d;
    for (int i = blockIdx.x * blockDim.x + threadIdx.x; i < n4;
         i += gridDim.x * blockDim.x) {
        float4 f = s4[i];
        short4v o;
        o[0] = f2bf(f.x); o[1] = f2bf(f.y); o[2] = f2bf(f.z); o[3] = f2bf(f.w);
        d4[i] = o;
    }
}

__global__ void init_kernel(unsigned int* ws)
{
    const int total = WS_ZERO_BYTES / 4;
    for (int i = blockIdx.x * blockDim.x + threadIdx.x; i < total;
         i += gridDim.x * blockDim.x)
        ws[i] = 0u;
}

// ---------------- kernel args ----------------
struct KArgs {
    const bf16 *xbf;
    const bf16 *eWhh0, *eWih1, *eWhh1, *dWhh0, *dWih1, *dWhh1, *eWih0, *dWih0;
    const float *ebih0, *ebhh0, *ebih1, *ebhh1, *dbih0, *dbhh0, *dbih1, *dbhh1;
    const float *fcW, *fcb;
    bf16 *h0a, *h0b, *h1a, *h1b;
    float *partials;
    unsigned *arrive, *release;
    float *outp;
};

// ---------------- grid barrier (fence-light) ----------------
// All cross-block data is written through (sc0 sc1) before arrival, so NO
// release fence (no buffer_wbl2). The single ACQUIRE atomic load per block
// emits the buffer_inv that makes subsequent cached reads refetch from L3.
__device__ __forceinline__ void gbar(unsigned* arrive, unsigned* release_f, unsigned gen)
{
    __syncthreads();   // each wave drains vmcnt -> all wt-stores at coherence point
    if (blockIdx.x == 0) {
        int t = threadIdx.x;
        if (t > 0 && t < NBLK) {
            while (load_dword_wt(arrive + t * 32) < gen)
                __builtin_amdgcn_s_sleep(2);
        }
        __syncthreads();
        if (t == 0) { vmcnt0(); store_dword_wt_u(release_f, gen); }
    } else {
        if (threadIdx.x == 0) {
            vmcnt0();
            store_dword_wt_u(arrive + blockIdx.x * 32, gen);
            while (load_dword_wt(release_f) < gen)
                __builtin_amdgcn_s_sleep(2);
        }
    }
    if (threadIdx.x == 0)
        (void)__hip_atomic_load(release_f, __ATOMIC_ACQUIRE, AGT);  // buffer_inv (L1+L2)
    __syncthreads();
}

// ---------------- LDS weight loaders ----------------
__device__ __forceinline__ void load_w0(char* lw, const bf16* Whh, const bf16* Wih, int j0, int tid)
{
    for (int u = tid; u < 64 * 68; u += 512) {
        int row = u / 68, uc = u - row * 68;
        int n = ((row >> 4) << 9) + j0 + (row & 15);
        int colel = uc << 3;
        short8 v = {0, 0, 0, 0, 0, 0, 0, 0};
        if (colel < 512)       v = *(const short8*)(Whh + (size_t)n * 512 + colel);
        else if (colel == 512) v = *(const short8*)(Wih + (size_t)n * 8);
        int off = row * W0_STRIDE + uc * 16;
        if (uc < 64) off ^= (row & 7) << 4;
        *(short8*)(lw + off) = v;
    }
}
__device__ __forceinline__ void load_w1(char* lw, const bf16* Wih, const bf16* Whh, int j0, int tid)
{
    for (int u = tid; u < 64 * 128; u += 512) {
        int row = u >> 7, uc = u & 127;
        int n = ((row >> 4) << 9) + j0 + (row & 15);
        int colel = uc << 3;
        short8 v;
        if (colel < 512) v = *(const short8*)(Wih + (size_t)n * 512 + colel);
        else             v = *(const short8*)(Whh + (size_t)n * 512 + (colel - 512));
        *(short8*)(lw + ((row * 2048 + uc * 16) ^ ((row & 7) << 4))) = v;
    }
}

// ---------------- layer-0 step (64 blocks: 2 m-halves x 32 j-blocks) ----------------
template<bool DEC>
__device__ __forceinline__ void l0_step(
    const bf16* __restrict__ h0cur, bf16* __restrict__ h0nxt,
    const bf16* __restrict__ xbf, int s,
    const float* __restrict__ partials, const float* __restrict__ fcb,
    float* __restrict__ outp, int t,
    char* lw, float* lgl, bf16* lxs,
    float* cst, const float* bsum,
    int m0, int j0, int jb, int tid)
{
    const int w = tid >> 6, g = w & 3, kh = w >> 2;
    const int l = tid & 63, lr = l & 15, lg = l >> 4;

    if (DEC) {
        #pragma unroll
        for (int p = 0; p < 2; ++p) {
            int e = p * 512 + tid, mlo = e >> 3, f = e & 7;
            if (t == 0) {
                lxs[mlo * 8 + f] = xbf[((size_t)(m0 + mlo) * 168 + 167) * 8 + f];
            } else {
                float sacc = fcb[f];
                #pragma unroll 8
                for (int q = 0; q < 32; ++q)
                    sacc += partials[q * 2048 + (m0 + mlo) * 8 + f];
                if (jb == 0) outp[(size_t)(m0 + mlo) * 192 + (t - 1) * 8 + f] = sacc;
                ((short*)lxs)[mlo * 8 + f] = f2bf(sacc);
            }
        }
        __syncthreads();
    }

    f32x4 acc[8];
    #pragma unroll
    for (int i = 0; i < 8; ++i) acc[i] = (f32x4){0.f, 0.f, 0.f, 0.f};
    const int wrow = g * 16 + lr;

    if (kh == 0) {
        #pragma unroll
        for (int kcg = 0; kcg < 9; ++kcg) {
            short8 bfr = *(const short8*)(lw + ((wrow * W0_STRIDE + kcg * 64 + lg * 16) ^ ((wrow & 7) << 4)));
            #pragma unroll
            for (int mt = 0; mt < 8; ++mt) {
                short8 av = *(const short8*)(h0cur + ((size_t)(m0 + mt * 16 + lr) << 9) + kcg * 32 + lg * 8);
                acc[mt] = __builtin_amdgcn_mfma_f32_16x16x32_bf16(av, bfr, acc[mt], 0, 0, 0);
            }
        }
    } else {
        #pragma unroll
        for (int kcg = 9; kcg < 17; ++kcg) {
            int off = wrow * W0_STRIDE + kcg * 64 + lg * 16;
            if (kcg < 16) off ^= (wrow & 7) << 4;
            short8 bfr = *(const short8*)(lw + off);
            #pragma unroll
            for (int mt = 0; mt < 8; ++mt) {
                short8 av;
                if (kcg < 16) {
                    av = *(const short8*)(h0cur + ((size_t)(m0 + mt * 16 + lr) << 9) + kcg * 32 + lg * 8);
                } else {
                    short8 z = {0, 0, 0, 0, 0, 0, 0, 0};
                    av = z;
                    if (lg == 0) {
                        if (DEC) av = *(const short8*)(lxs + (mt * 16 + lr) * 8);
                        else     av = *(const short8*)(xbf + ((size_t)(m0 + mt * 16 + lr) * 168 + s) * 8);
                    }
                }
                acc[mt] = __builtin_amdgcn_mfma_f32_16x16x32_bf16(av, bfr, acc[mt], 0, 0, 0);
            }
        }
    }

    __syncthreads();
    if (kh == 0) {
        #pragma unroll
        for (int mt = 0; mt < 8; ++mt)
            #pragma unroll
            for (int r = 0; r < 4; ++r)
                lgl[(g * 128 + mt * 16 + lg * 4 + r) * 16 + lr] = acc[mt][r];
    }
    __syncthreads();
    if (kh == 1) {
        #pragma unroll
        for (int mt = 0; mt < 8; ++mt)
            #pragma unroll
            for (int r = 0; r < 4; ++r)
                lgl[(g * 128 + mt * 16 + lg * 4 + r) * 16 + lr] += acc[mt][r];
    }
    __syncthreads();

    const int jl = tid & 15, mb = tid >> 4;
    #pragma unroll
    for (int p = 0; p < 4; ++p) {
        int ml = p * 32 + mb;
        float gi = lgl[(0 * 128 + ml) * 16 + jl] + bsum[0];
        float gf = lgl[(1 * 128 + ml) * 16 + jl] + bsum[1];
        float gg = lgl[(2 * 128 + ml) * 16 + jl] + bsum[2];
        float go = lgl[(3 * 128 + ml) * 16 + jl] + bsum[3];
        float cv = sigm(gf) * cst[p] + sigm(gi) * tanhf(gg);
        float hv = sigm(go) * tanhf(cv);
        cst[p] = cv;
        store_short_wt(h0nxt + ((size_t)(m0 + ml) << 9) + j0 + jl, f2bf(hv));
    }
}

// ---------------- layer-1 step (128 blocks: 4 m-quarters x 32 j-blocks) ----------------
template<bool DEC>
__device__ __forceinline__ void l1_step(
    const bf16* __restrict__ h0src, const bf16* __restrict__ h1prev, bf16* __restrict__ h1nxt,
    float* __restrict__ partials, const float* __restrict__ wf,
    char* lw, float* lgl,
    float* cst, const float* bsum,
    int m0, int j0, int jb, int tid)
{
    const int w = tid >> 6, g = w & 3;
    const int l = tid & 63, lr = l & 15, lg = l >> 4;
    const bf16* A = (w < 4) ? h0src : h1prev;
    const int colbase = (w < 4) ? 0 : 1024;
    const int wrow = g * 16 + lr;

    f32x4 acc[4];
    #pragma unroll
    for (int i = 0; i < 4; ++i) acc[i] = (f32x4){0.f, 0.f, 0.f, 0.f};

    #pragma unroll
    for (int kc = 0; kc < 16; ++kc) {
        short8 bfr = *(const short8*)(lw + ((wrow * 2048 + colbase + kc * 64 + lg * 16) ^ ((wrow & 7) << 4)));
        #pragma unroll
        for (int mt = 0; mt < 4; ++mt) {
            short8 av = *(const short8*)(A + ((size_t)(m0 + mt * 16 + lr) << 9) + kc * 32 + lg * 8);
            acc[mt] = __builtin_amdgcn_mfma_f32_16x16x32_bf16(av, bfr, acc[mt], 0, 0, 0);
        }
    }

    __syncthreads();
    if (w < 4) {
        #pragma unroll
        for (int mt = 0; mt < 4; ++mt)
            #pragma unroll
            for (int r = 0; r < 4; ++r)
                lgl[(g * 64 + mt * 16 + lg * 4 + r) * 16 + lr] = acc[mt][r];
    }
    __syncthreads();
    if (w >= 4) {
        #pragma unroll
        for (int mt = 0; mt < 4; ++mt)
            #pragma unroll
            for (int r = 0; r < 4; ++r)
                lgl[(g * 64 + mt * 16 + lg * 4 + r) * 16 + lr] += acc[mt][r];
    }
    __syncthreads();

    const int jl = tid & 15, mb = tid >> 4;
    #pragma unroll
    for (int p = 0; p < 2; ++p) {
        int ml = p * 32 + mb;
        float gi = lgl[(0 * 64 + ml) * 16 + jl] + bsum[0];
        float gf = lgl[(1 * 64 + ml) * 16 + jl] + bsum[1];
        float gg = lgl[(2 * 64 + ml) * 16 + jl] + bsum[2];
        float go = lgl[(3 * 64 + ml) * 16 + jl] + bsum[3];
        float cv = sigm(gf) * cst[p] + sigm(gi) * tanhf(gg);
        float hv = sigm(go) * tanhf(cv);
        cst[p] = cv;
        store_short_wt(h1nxt + ((size_t)(m0 + ml) << 9) + j0 + jl, f2bf(hv));
        if (DEC) {
            #pragma unroll
            for (int f = 0; f < 8; ++f) {
                float v = hv * wf[f];
                v += __shfl_xor(v, 1); v += __shfl_xor(v, 2);
                v += __shfl_xor(v, 4); v += __shfl_xor(v, 8);
                if (jl == f)
                    store_dword_wt(partials + jb * 2048 + (m0 + ml) * 8 + f, v);
            }
        }
    }
}

// ---------------- persistent kernel ----------------
__global__ __launch_bounds__(512, 2) void net_kernel(KArgs a)
{
    extern __shared__ char smem[];
    const int tid = threadIdx.x;
    const int bid = blockIdx.x;
    const int role = (bid < 64) ? 0 : 1;
    const int sub = role == 0 ? bid : bid - 64;
    const int jb = sub & 31;
    const int mh = sub >> 5;
    const int m0 = (role == 0) ? mh * 128 : mh * 64;
    const int j0 = jb * 16;

    char* lw  = smem;
    float* lgl = (float*)(smem + (role == 0 ? 64 * W0_STRIDE : 131072));
    bf16* lxs  = (bf16*)(smem + 64 * W0_STRIDE + 32768);

    if (role == 0) load_w0(lw, a.eWhh0, a.eWih0, j0, tid);
    else           load_w1(lw, a.eWih1, a.eWhh1, j0, tid);

    float bsum[4];
    {
        const float* bi = role == 0 ? a.ebih0 : a.ebih1;
        const float* bh = role == 0 ? a.ebhh0 : a.ebhh1;
        #pragma unroll
        for (int g2 = 0; g2 < 4; ++g2) {
            int n = (g2 << 9) + j0 + (tid & 15);
            bsum[g2] = bi[n] + bh[n];
        }
    }
    float cst[4] = {0.f, 0.f, 0.f, 0.f};
    __syncthreads();

    bf16* H0[2] = { a.h0a, a.h0b };
    bf16* H1[2] = { a.h1a, a.h1b };
    unsigned gen = 1;

    // -------- encoder --------
    for (int s = 0; s <= 168; ++s) {
        if (role == 0) {
            if (s < 168)
                l0_step<false>(H0[s & 1], H0[(s + 1) & 1], a.xbf, s,
                               nullptr, nullptr, nullptr, 0,
                               lw, lgl, lxs, cst, bsum, m0, j0, jb, tid);
        } else {
            if (s >= 1)
                l1_step<false>(H0[s & 1], H1[(s + 1) & 1], H1[s & 1],
                               nullptr, nullptr, lw, lgl, cst, bsum, m0, j0, jb, tid);
        }
        gbar(a.arrive, a.release, gen++);
    }

    // -------- switch to decoder weights --------
    if (role == 0) load_w0(lw, a.dWhh0, a.dWih0, j0, tid);
    else           load_w1(lw, a.dWih1, a.dWhh1, j0, tid);
    {
        const float* bi = role == 0 ? a.dbih0 : a.dbih1;
        const float* bh = role == 0 ? a.dbhh0 : a.dbhh1;
        #pragma unroll
        for (int g2 = 0; g2 < 4; ++g2) {
            int n = (g2 << 9) + j0 + (tid & 15);
            bsum[g2] = bi[n] + bh[n];
        }
    }
    float wf[8] = {0.f, 0.f, 0.f, 0.f, 0.f, 0.f, 0.f, 0.f};
    if (role == 1) {
        #pragma unroll
        for (int f = 0; f < 8; ++f) wf[f] = a.fcW[f * 512 + j0 + (tid & 15)];
    }
    __syncthreads();

    // -------- decoder --------
    for (int t = 0; t < 24; ++t) {
        if (role == 0)
            l0_step<true>(H0[t & 1], H0[(t + 1) & 1], a.xbf, 0,
                          a.partials, a.fcb, a.outp, t,
                          lw, lgl, lxs, cst, bsum, m0, j0, jb, tid);
        gbar(a.arrive, a.release, gen++);
        if (role == 1)
            l1_step<true>(H0[(t + 1) & 1], H1[t & 1], H1[(t + 1) & 1],
                          a.partials, wf, lw, lgl, cst, bsum, m0, j0, jb, tid);
        gbar(a.arrive, a.release, gen++);
    }

    // -------- final pred[23] --------
    if (role == 0 && jb == 0) {
        #pragma unroll
        for (int p = 0; p < 2; ++p) {
            int e = p * 512 + tid, mlo = e >> 3, f = e & 7;
            float sacc = a.fcb[f];
            #pragma unroll 8
            for (int q = 0; q < 32; ++q)
                sacc += a.partials[q * 2048 + (m0 + mlo) * 8 + f];
            a.outp[(size_t)(m0 + mlo) * 192 + 23 * 8 + f] = sacc;
        }
    }
}

extern "C" void kernel_launch(void* const* d_in, const int* in_sizes, int n_in,
                              void* d_out, int out_size, void* d_ws, size_t ws_size,
                              hipStream_t stream)
{
    (void)in_sizes; (void)n_in; (void)out_size; (void)ws_size;
    const float* src   = (const float*)d_in[0];
    const float* eWih0 = (const float*)d_in[1];
    const float* eWhh0 = (const float*)d_in[2];
    const float* ebih0 = (const float*)d_in[3];
    const float* ebhh0 = (const float*)d_in[4];
    const float* eWih1 = (const float*)d_in[5];
    const float* eWhh1 = (const float*)d_in[6];
    const float* ebih1 = (const float*)d_in[7];
    const float* ebhh1 = (const float*)d_in[8];
    const float* dWih0 = (const float*)d_in[9];
    const float* dWhh0 = (const float*)d_in[10];
    const float* dbih0 = (const float*)d_in[11];
    const float* dbhh0 = (const float*)d_in[12];
    const float* dWih1 = (const float*)d_in[13];
    const float* dWhh1 = (const float*)d_in[14];
    const float* dbih1 = (const float*)d_in[15];
    const float* dbhh1 = (const float*)d_in[16];
    const float* fcW   = (const float*)d_in[17];
    const float* fcb   = (const float*)d_in[18];

    char* ws = (char*)d_ws;
    const int NH = 2048 * 512;

    CvtArgs ca;
    ca.e[0] = { eWhh0, (bf16*)(ws + WS_W + 0x000000), NH };
    ca.e[1] = { eWih1, (bf16*)(ws + WS_W + 0x200000), NH };
    ca.e[2] = { eWhh1, (bf16*)(ws + WS_W + 0x400000), NH };
    ca.e[3] = { dWhh0, (bf16*)(ws + WS_W + 0x600000), NH };
    ca.e[4] = { dWih1, (bf16*)(ws + WS_W + 0x800000), NH };
    ca.e[5] = { dWhh1, (bf16*)(ws + WS_W + 0xA00000), NH };
    ca.e[6] = { eWih0, (bf16*)(ws + WS_EWIH0), 2048 * 8 };
    ca.e[7] = { dWih0, (bf16*)(ws + WS_DWIH0), 2048 * 8 };
    ca.e[8] = { src,   (bf16*)(ws + WS_XBF),   256 * 168 * 8 };

    KArgs ka;
    ka.xbf   = (const bf16*)(ws + WS_XBF);
    ka.eWhh0 = (const bf16*)(ws + WS_W + 0x000000);
    ka.eWih1 = (const bf16*)(ws + WS_W + 0x200000);
    ka.eWhh1 = (const bf16*)(ws + WS_W + 0x400000);
    ka.dWhh0 = (const bf16*)(ws + WS_W + 0x600000);
    ka.dWih1 = (const bf16*)(ws + WS_W + 0x800000);
    ka.dWhh1 = (const bf16*)(ws + WS_W + 0xA00000);
    ka.eWih0 = (const bf16*)(ws + WS_EWIH0);
    ka.dWih0 = (const bf16*)(ws + WS_DWIH0);
    ka.ebih0 = ebih0; ka.ebhh0 = ebhh0; ka.ebih1 = ebih1; ka.ebhh1 = ebhh1;
    ka.dbih0 = dbih0; ka.dbhh0 = dbhh0; ka.dbih1 = dbih1; ka.dbhh1 = dbhh1;
    ka.fcW = fcW; ka.fcb = fcb;
    ka.h0a = (bf16*)(ws + WS_H0);
    ka.h0b = (bf16*)(ws + WS_H0 + 0x40000);
    ka.h1a = (bf16*)(ws + WS_H1);
    ka.h1b = (bf16*)(ws + WS_H1 + 0x40000);
    ka.partials = (float*)(ws + WS_PART);
    ka.arrive   = (unsigned*)(ws + WS_ARRIVE);
    ka.release  = (unsigned*)(ws + WS_RELEASE);
    ka.outp     = (float*)d_out;

    hipFuncSetAttribute((const void*)net_kernel,
                        hipFuncAttributeMaxDynamicSharedMemorySize, SMEM_BYTES);

    convert_kernel<<<dim3(128, 9), dim3(256), 0, stream>>>(ca);
    init_kernel<<<dim3(512), dim3(256), 0, stream>>>((unsigned int*)ws);
    net_kernel<<<dim3(NBLK), dim3(512), SMEM_BYTES, stream>>>(ka);
}

// Round 7
// 3154.211 us; speedup vs baseline: 1.6252x; 1.3803x over previous
//
#include <hip/hip_runtime.h>
#include <hip/hip_bf16.h>

typedef __hip_bfloat16 bf16;
typedef __attribute__((ext_vector_type(8))) short short8;
typedef __attribute__((ext_vector_type(4))) short short4v;
typedef __attribute__((ext_vector_type(4))) float f32x4;

#define NBLK 192
#define SMEM_BYTES 147456
#define W0_STRIDE 1152   // 9*128 -> XOR swizzle row-closed

__device__ __forceinline__ float sigm(float x) { return 1.0f / (1.0f + __expf(-x)); }

__device__ __forceinline__ short f2bf(float f) {
    union { float f; unsigned int u; } v; v.f = f;
    unsigned int r = v.u + 0x7fffu + ((v.u >> 16) & 1u);
    return (short)(r >> 16);
}

// ---- coherence-point (L1+L2 bypass) ops: producer writes through, consumer
// ---- reads through. NO buffer_inv / wbl2 anywhere in the main loop.
__device__ __forceinline__ void store_short_wt(bf16* p, short v) {
    asm volatile("global_store_short %0, %1, off sc0 sc1"
                 :: "v"(p), "v"((int)(unsigned short)v) : "memory");
}
__device__ __forceinline__ void store_dword_wt(float* p, float v) {
    asm volatile("global_store_dword %0, %1, off sc0 sc1"
                 :: "v"(p), "v"(v) : "memory");
}
__device__ __forceinline__ void store_dword_wt_u(unsigned* p, unsigned v) {
    asm volatile("global_store_dword %0, %1, off sc0 sc1"
                 :: "v"(p), "v"(v) : "memory");
}
__device__ __forceinline__ unsigned poll_dword_wt(const unsigned* p) {   // waits inside
    unsigned v;
    asm volatile("global_load_dword %0, %1, off sc0 sc1\n\ts_waitcnt vmcnt(0)"
                 : "=v"(v) : "v"(p) : "memory");
    return v;
}
__device__ __forceinline__ short8 load_b16x8_wt(const bf16* p) {         // NO wait inside
    short8 v;
    asm volatile("global_load_dwordx4 %0, %1, off sc0 sc1"
                 : "=v"(v) : "v"(p) : "memory");
    return v;
}
__device__ __forceinline__ float load_f32_wt(const float* p) {           // NO wait inside
    float v;
    asm volatile("global_load_dword %0, %1, off sc0 sc1"
                 : "=v"(v) : "v"(p) : "memory");
    return v;
}
__device__ __forceinline__ void vmcnt0() {
    asm volatile("s_waitcnt vmcnt(0)" ::: "memory");
}
__device__ __forceinline__ void ldrain() {   // order VALU consumers after the wait (rule #18)
    vmcnt0();
    __builtin_amdgcn_sched_barrier(0);
}

// ---------------- workspace layout ----------------
#define WS_H0      0x000000
#define WS_H1      0x080000
#define WS_PART    0x100000
#define WS_ARRIVE  0x140000
#define WS_RELEASE 0x148000
#define WS_XBF     0x150000
#define WS_W       0x200000
#define WS_EWIH0   0xE00000
#define WS_DWIH0   0xE08000
#define WS_ZERO_BYTES 0x150000

// ---------------- fp32 -> bf16 conversion ----------------
struct CvtEntry { const float* s; bf16* d; int n; };
struct CvtArgs  { CvtEntry e[9]; };

__global__ __launch_bounds__(256) void convert_kernel(CvtArgs a)
{
    CvtEntry en = a.e[blockIdx.y];
    int n4 = en.n >> 2;
    const float4* s4 = (const float4*)en.s;
    short4v* d4 = (short4v*)en.d;
    for (int i = blockIdx.x * blockDim.x + threadIdx.x; i < n4;
         i += gridDim.x * blockDim.x) {
        float4 f = s4[i];
        short4v o;
        o[0] = f2bf(f.x); o[1] = f2bf(f.y); o[2] = f2bf(f.z); o[3] = f2bf(f.w);
        d4[i] = o;
    }
}

__global__ void init_kernel(unsigned int* ws)
{
    const int total = WS_ZERO_BYTES / 4;
    for (int i = blockIdx.x * blockDim.x + threadIdx.x; i < total;
         i += gridDim.x * blockDim.x)
        ws[i] = 0u;
}

// ---------------- kernel args ----------------
struct KArgs {
    const bf16 *xbf;
    const bf16 *eWhh0, *eWih1, *eWhh1, *dWhh0, *dWih1, *dWhh1, *eWih0, *dWih0;
    const float *ebih0, *ebhh0, *ebih1, *ebhh1, *dbih0, *dbhh0, *dbih1, *dbhh1;
    const float *fcW, *fcb;
    bf16 *h0a, *h0b, *h1a, *h1b;
    float *partials;
    unsigned *arrive, *release;
    float *outp;
};

// ---------------- grid barrier: flags at coherence point, NO cache inv ----------------
__device__ __forceinline__ void gbar(unsigned* arrive, unsigned* release_f, unsigned gen)
{
    vmcnt0();          // each wave's wt-stores are at the coherence point
    __syncthreads();
    if (blockIdx.x == 0) {
        int t = threadIdx.x;
        if (t > 0 && t < NBLK) {
            while (poll_dword_wt(arrive + t * 32) < gen)
                __builtin_amdgcn_s_sleep(1);
        }
        __syncthreads();
        if (t == 0) store_dword_wt_u(release_f, gen);
    } else {
        if (threadIdx.x == 0) {
            store_dword_wt_u(arrive + blockIdx.x * 32, gen);
            while (poll_dword_wt(release_f) < gen)
                __builtin_amdgcn_s_sleep(1);
        }
    }
    __syncthreads();
}

// ---------------- LDS weight loaders (unchanged, verified) ----------------
__device__ __forceinline__ void load_w0(char* lw, const bf16* Whh, const bf16* Wih, int j0, int tid)
{
    for (int u = tid; u < 64 * 68; u += 512) {
        int row = u / 68, uc = u - row * 68;
        int n = ((row >> 4) << 9) + j0 + (row & 15);
        int colel = uc << 3;
        short8 v = {0, 0, 0, 0, 0, 0, 0, 0};
        if (colel < 512)       v = *(const short8*)(Whh + (size_t)n * 512 + colel);
        else if (colel == 512) v = *(const short8*)(Wih + (size_t)n * 8);
        int off = row * W0_STRIDE + uc * 16;
        if (uc < 64) off ^= (row & 7) << 4;
        *(short8*)(lw + off) = v;
    }
}
__device__ __forceinline__ void load_w1(char* lw, const bf16* Wih, const bf16* Whh, int j0, int tid)
{
    for (int u = tid; u < 64 * 128; u += 512) {
        int row = u >> 7, uc = u & 127;
        int n = ((row >> 4) << 9) + j0 + (row & 15);
        int colel = uc << 3;
        short8 v;
        if (colel < 512) v = *(const short8*)(Wih + (size_t)n * 512 + colel);
        else             v = *(const short8*)(Whh + (size_t)n * 512 + (colel - 512));
        *(short8*)(lw + ((row * 2048 + uc * 16) ^ ((row & 7) << 4))) = v;
    }
}

// ---------------- layer-0 step: wave w owns m-tile w (16 rows), all 4 gates ----------------
// No inter-wave reduction; activation fully in-lane.
template<bool DEC>
__device__ __forceinline__ void l0_step(
    const bf16* __restrict__ h0cur, bf16* __restrict__ h0nxt,
    const bf16* __restrict__ xbf, int s,
    const float* __restrict__ partials, const float* __restrict__ fcb,
    float* __restrict__ outp, int t,
    char* lw, bf16* lxs,
    float* cst, const float* bsum,
    int m0, int j0, int jb, int tid)
{
    const int w = tid >> 6;          // m-tile 0..7
    const int l = tid & 63, lr = l & 15, lg = l >> 4;

    if (DEC) {
        // build x_stage (t==0: last src step; t>0: reduce fc partials = pred[t-1])
        #pragma unroll
        for (int p = 0; p < 2; ++p) {
            int e = p * 512 + tid, mlo = e >> 3, f = e & 7;
            if (t == 0) {
                lxs[mlo * 8 + f] = xbf[((size_t)(m0 + mlo) * 168 + 167) * 8 + f];
            } else {
                float pv[32];
                #pragma unroll
                for (int q = 0; q < 32; ++q)
                    pv[q] = load_f32_wt(partials + q * 2048 + (m0 + mlo) * 8 + f);
                ldrain();
                float sacc = fcb[f];
                #pragma unroll
                for (int q = 0; q < 32; ++q) sacc += pv[q];
                if (jb == 0) outp[(size_t)(m0 + mlo) * 192 + (t - 1) * 8 + f] = sacc;
                ((short*)lxs)[mlo * 8 + f] = f2bf(sacc);
            }
        }
        __syncthreads();
    }

    // preload 16 A-frags (own rows, read exactly once, coherence-point loads)
    const bf16* arow = h0cur + ((size_t)(m0 + w * 16 + lr) << 9) + lg * 8;
    short8 afr[16];
    #pragma unroll
    for (int kcg = 0; kcg < 16; ++kcg)
        afr[kcg] = load_b16x8_wt(arow + kcg * 32);
    short8 ax = {0, 0, 0, 0, 0, 0, 0, 0};
    if (lg == 0) {
        if (DEC) ax = *(const short8*)(lxs + (w * 16 + lr) * 8);
        else     ax = *(const short8*)(xbf + ((size_t)(m0 + w * 16 + lr) * 168 + s) * 8);
    }
    ldrain();

    f32x4 acc[4];
    #pragma unroll
    for (int g = 0; g < 4; ++g) acc[g] = (f32x4){0.f, 0.f, 0.f, 0.f};

    #pragma unroll
    for (int kcg = 0; kcg < 17; ++kcg) {
        #pragma unroll
        for (int g = 0; g < 4; ++g) {
            int wrow = g * 16 + lr;
            int off = wrow * W0_STRIDE + kcg * 64 + lg * 16;
            if (kcg < 16) off ^= (wrow & 7) << 4;
            short8 bfr = *(const short8*)(lw + off);
            short8 av = (kcg < 16) ? afr[kcg] : ax;
            acc[g] = __builtin_amdgcn_mfma_f32_16x16x32_bf16(av, bfr, acc[g], 0, 0, 0);
        }
    }

    // in-lane activation: C layout col=lr, row = lg*4 + r  (within wave's m-tile)
    #pragma unroll
    for (int r = 0; r < 4; ++r) {
        float gi = acc[0][r] + bsum[0];
        float gf = acc[1][r] + bsum[1];
        float gg = acc[2][r] + bsum[2];
        float go = acc[3][r] + bsum[3];
        float cv = sigm(gf) * cst[r] + sigm(gi) * tanhf(gg);
        float hv = sigm(go) * tanhf(cv);
        cst[r] = cv;
        store_short_wt(h0nxt + ((size_t)(m0 + w * 16 + lg * 4 + r) << 9) + j0 + lr, f2bf(hv));
    }
}

// ---------------- layer-1 step: wave (mt=w&3, kh=w>>2); 2-way k-half reduction ----------------
template<bool DEC>
__device__ __forceinline__ void l1_step(
    const bf16* __restrict__ h0src, const bf16* __restrict__ h1prev, bf16* __restrict__ h1nxt,
    float* __restrict__ partials, const float* __restrict__ wf,
    char* lw, float* lgl,
    float* cst, const float* bsum,
    int m0, int j0, int jb, int tid)
{
    const int w = tid >> 6, mt = w & 3, kh = w >> 2;
    const int l = tid & 63, lr = l & 15, lg = l >> 4;
    const bf16* A = (kh == 0) ? h0src : h1prev;
    const int colbase = (kh == 0) ? 0 : 1024;

    const bf16* arow = A + ((size_t)(m0 + mt * 16 + lr) << 9) + lg * 8;
    short8 afr[16];
    #pragma unroll
    for (int kc = 0; kc < 16; ++kc)
        afr[kc] = load_b16x8_wt(arow + kc * 32);
    ldrain();

    f32x4 acc[4];
    #pragma unroll
    for (int g = 0; g < 4; ++g) acc[g] = (f32x4){0.f, 0.f, 0.f, 0.f};

    #pragma unroll
    for (int kc = 0; kc < 16; ++kc) {
        #pragma unroll
        for (int g = 0; g < 4; ++g) {
            int wrow = g * 16 + lr;
            short8 bfr = *(const short8*)(lw + ((wrow * 2048 + colbase + kc * 64 + lg * 16) ^ ((wrow & 7) << 4)));
            acc[g] = __builtin_amdgcn_mfma_f32_16x16x32_bf16(afr[kc], bfr, acc[g], 0, 0, 0);
        }
    }

    if (kh == 1) {
        #pragma unroll
        for (int g = 0; g < 4; ++g)
            #pragma unroll
            for (int r = 0; r < 4; ++r)
                lgl[(g * 64 + mt * 16 + lg * 4 + r) * 16 + lr] = acc[g][r];
    }
    __syncthreads();
    if (kh == 0) {
        #pragma unroll
        for (int r = 0; r < 4; ++r) {
            int mrow = mt * 16 + lg * 4 + r;
            float gi = acc[0][r] + lgl[(0 * 64 + mrow) * 16 + lr] + bsum[0];
            float gf = acc[1][r] + lgl[(1 * 64 + mrow) * 16 + lr] + bsum[1];
            float gg = acc[2][r] + lgl[(2 * 64 + mrow) * 16 + lr] + bsum[2];
            float go = acc[3][r] + lgl[(3 * 64 + mrow) * 16 + lr] + bsum[3];
            float cv = sigm(gf) * cst[r] + sigm(gi) * tanhf(gg);
            float hv = sigm(go) * tanhf(cv);
            cst[r] = cv;
            store_short_wt(h1nxt + ((size_t)(m0 + mrow) << 9) + j0 + lr, f2bf(hv));
            if (DEC) {
                #pragma unroll
                for (int f = 0; f < 8; ++f) {
                    float v = hv * wf[f];
                    v += __shfl_xor(v, 1); v += __shfl_xor(v, 2);
                    v += __shfl_xor(v, 4); v += __shfl_xor(v, 8);
                    if (lr == f)
                        store_dword_wt(partials + jb * 2048 + (m0 + mrow) * 8 + f, v);
                }
            }
        }
    }
}

// ---------------- persistent kernel ----------------
__global__ __launch_bounds__(512, 2) void net_kernel(KArgs a)
{
    extern __shared__ char smem[];
    const int tid = threadIdx.x;
    const int bid = blockIdx.x;
    const int role = (bid < 64) ? 0 : 1;
    const int sub = role == 0 ? bid : bid - 64;
    const int jb = sub & 31;
    const int mh = sub >> 5;
    const int m0 = (role == 0) ? mh * 128 : mh * 64;
    const int j0 = jb * 16;

    char* lw  = smem;
    float* lgl = (float*)(smem + 131072);               // role 1 only (16KB)
    bf16* lxs  = (bf16*)(smem + 64 * W0_STRIDE);        // role 0 only (2KB)

    if (role == 0) load_w0(lw, a.eWhh0, a.eWih0, j0, tid);
    else           load_w1(lw, a.eWih1, a.eWhh1, j0, tid);

    float bsum[4];
    {
        const float* bi = role == 0 ? a.ebih0 : a.ebih1;
        const float* bh = role == 0 ? a.ebhh0 : a.ebhh1;
        #pragma unroll
        for (int g2 = 0; g2 < 4; ++g2) {
            int n = (g2 << 9) + j0 + (tid & 15);
            bsum[g2] = bi[n] + bh[n];
        }
    }
    float cst[4] = {0.f, 0.f, 0.f, 0.f};
    __syncthreads();

    bf16* H0[2] = { a.h0a, a.h0b };
    bf16* H1[2] = { a.h1a, a.h1b };
    unsigned gen = 1;

    // -------- encoder --------
    for (int s = 0; s <= 168; ++s) {
        if (role == 0) {
            if (s < 168)
                l0_step<false>(H0[s & 1], H0[(s + 1) & 1], a.xbf, s,
                               nullptr, nullptr, nullptr, 0,
                               lw, lxs, cst, bsum, m0, j0, jb, tid);
        } else {
            if (s >= 1)
                l1_step<false>(H0[s & 1], H1[(s + 1) & 1], H1[s & 1],
                               nullptr, nullptr, lw, lgl, cst, bsum, m0, j0, jb, tid);
        }
        gbar(a.arrive, a.release, gen++);
    }

    // -------- switch to decoder weights --------
    if (role == 0) load_w0(lw, a.dWhh0, a.dWih0, j0, tid);
    else           load_w1(lw, a.dWih1, a.dWhh1, j0, tid);
    {
        const float* bi = role == 0 ? a.dbih0 : a.dbih1;
        const float* bh = role == 0 ? a.dbhh0 : a.dbhh1;
        #pragma unroll
        for (int g2 = 0; g2 < 4; ++g2) {
            int n = (g2 << 9) + j0 + (tid & 15);
            bsum[g2] = bi[n] + bh[n];
        }
    }
    float wf[8] = {0.f, 0.f, 0.f, 0.f, 0.f, 0.f, 0.f, 0.f};
    if (role == 1) {
        #pragma unroll
        for (int f = 0; f < 8; ++f) wf[f] = a.fcW[f * 512 + j0 + (tid & 15)];
    }
    __syncthreads();

    // -------- decoder --------
    for (int t = 0; t < 24; ++t) {
        if (role == 0)
            l0_step<true>(H0[t & 1], H0[(t + 1) & 1], a.xbf, 0,
                          a.partials, a.fcb, a.outp, t,
                          lw, lxs, cst, bsum, m0, j0, jb, tid);
        gbar(a.arrive, a.release, gen++);
        if (role == 1)
            l1_step<true>(H0[(t + 1) & 1], H1[t & 1], H1[(t + 1) & 1],
                          a.partials, wf, lw, lgl, cst, bsum, m0, j0, jb, tid);
        gbar(a.arrive, a.release, gen++);
    }

    // -------- final pred[23] --------
    if (role == 0 && jb == 0) {
        #pragma unroll
        for (int p = 0; p < 2; ++p) {
            int e = p * 512 + tid, mlo = e >> 3, f = e & 7;
            float pv[32];
            #pragma unroll
            for (int q = 0; q < 32; ++q)
                pv[q] = load_f32_wt(a.partials + q * 2048 + (m0 + mlo) * 8 + f);
            ldrain();
            float sacc = a.fcb[f];
            #pragma unroll
            for (int q = 0; q < 32; ++q) sacc += pv[q];
            a.outp[(size_t)(m0 + mlo) * 192 + 23 * 8 + f] = sacc;
        }
    }
}

extern "C" void kernel_launch(void* const* d_in, const int* in_sizes, int n_in,
                              void* d_out, int out_size, void* d_ws, size_t ws_size,
                              hipStream_t stream)
{
    (void)in_sizes; (void)n_in; (void)out_size; (void)ws_size;
    const float* src   = (const float*)d_in[0];
    const float* eWih0 = (const float*)d_in[1];
    const float* eWhh0 = (const float*)d_in[2];
    const float* ebih0 = (const float*)d_in[3];
    const float* ebhh0 = (const float*)d_in[4];
    const float* eWih1 = (const float*)d_in[5];
    const float* eWhh1 = (const float*)d_in[6];
    const float* ebih1 = (const float*)d_in[7];
    const float* ebhh1 = (const float*)d_in[8];
    const float* dWih0 = (const float*)d_in[9];
    const float* dWhh0 = (const float*)d_in[10];
    const float* dbih0 = (const float*)d_in[11];
    const float* dbhh0 = (const float*)d_in[12];
    const float* dWih1 = (const float*)d_in[13];
    const float* dWhh1 = (const float*)d_in[14];
    const float* dbih1 = (const float*)d_in[15];
    const float* dbhh1 = (const float*)d_in[16];
    const float* fcW   = (const float*)d_in[17];
    const float* fcb   = (const float*)d_in[18];

    char* ws = (char*)d_ws;
    const int NH = 2048 * 512;

    CvtArgs ca;
    ca.e[0] = { eWhh0, (bf16*)(ws + WS_W + 0x000000), NH };
    ca.e[1] = { eWih1, (bf16*)(ws + WS_W + 0x200000), NH };
    ca.e[2] = { eWhh1, (bf16*)(ws + WS_W + 0x400000), NH };
    ca.e[3] = { dWhh0, (bf16*)(ws + WS_W + 0x600000), NH };
    ca.e[4] = { dWih1, (bf16*)(ws + WS_W + 0x800000), NH };
    ca.e[5] = { dWhh1, (bf16*)(ws + WS_W + 0xA00000), NH };
    ca.e[6] = { eWih0, (bf16*)(ws + WS_EWIH0), 2048 * 8 };
    ca.e[7] = { dWih0, (bf16*)(ws + WS_DWIH0), 2048 * 8 };
    ca.e[8] = { src,   (bf16*)(ws + WS_XBF),   256 * 168 * 8 };

    KArgs ka;
    ka.xbf   = (const bf16*)(ws + WS_XBF);
    ka.eWhh0 = (const bf16*)(ws + WS_W + 0x000000);
    ka.eWih1 = (const bf16*)(ws + WS_W + 0x200000);
    ka.eWhh1 = (const bf16*)(ws + WS_W + 0x400000);
    ka.dWhh0 = (const bf16*)(ws + WS_W + 0x600000);
    ka.dWih1 = (const bf16*)(ws + WS_W + 0x800000);
    ka.dWhh1 = (const bf16*)(ws + WS_W + 0xA00000);
    ka.eWih0 = (const bf16*)(ws + WS_EWIH0);
    ka.dWih0 = (const bf16*)(ws + WS_DWIH0);
    ka.ebih0 = ebih0; ka.ebhh0 = ebhh0; ka.ebih1 = ebih1; ka.ebhh1 = ebhh1;
    ka.dbih0 = dbih0; ka.dbhh0 = dbhh0; ka.dbih1 = dbih1; ka.dbhh1 = dbhh1;
    ka.fcW = fcW; ka.fcb = fcb;
    ka.h0a = (bf16*)(ws + WS_H0);
    ka.h0b = (bf16*)(ws + WS_H0 + 0x40000);
    ka.h1a = (bf16*)(ws + WS_H1);
    ka.h1b = (bf16*)(ws + WS_H1 + 0x40000);
    ka.partials = (float*)(ws + WS_PART);
    ka.arrive   = (unsigned*)(ws + WS_ARRIVE);
    ka.release  = (unsigned*)(ws + WS_RELEASE);
    ka.outp     = (float*)d_out;

    hipFuncSetAttribute((const void*)net_kernel,
                        hipFuncAttributeMaxDynamicSharedMemorySize, SMEM_BYTES);

    convert_kernel<<<dim3(128, 9), dim3(256), 0, stream>>>(ca);
    init_kernel<<<dim3(512), dim3(256), 0, stream>>>((unsigned int*)ws);
    net_kernel<<<dim3(NBLK), dim3(512), SMEM_BYTES, stream>>>(ka);
}